// Round 14
// baseline (69.808 us; speedup 1.0000x reference)
//
#include <hip/hip_runtime.h>
#include <hip/hip_bf16.h>

typedef __attribute__((ext_vector_type(8))) short bf16x8;
typedef __attribute__((ext_vector_type(4))) float f32x4;

#define MFMA16(A,B,C) __builtin_amdgcn_mfma_f32_16x16x32_bf16((A),(B),(C),0,0,0)

static __device__ __forceinline__ f32x4 ld4(const float* p){
  return *(const f32x4*)p;
}
static __device__ __forceinline__ unsigned pk2(float a, float b){
  unsigned r;
  asm("v_cvt_pk_bf16_f32 %0, %1, %2" : "=v"(r) : "v"(a), "v"(b));
  return r;
}
static __device__ __forceinline__ bf16x8 mk8(float a,float b,float c,float d,
                                             float e,float f,float g,float h){
  union { bf16x8 v; unsigned u[4]; } r;
  r.u[0]=pk2(a,b); r.u[1]=pk2(c,d); r.u[2]=pk2(e,f); r.u[3]=pk2(g,h);
  return r.v;
}
static __device__ __forceinline__ bf16x8 mk8v(f32x4 a, f32x4 b){
  return mk8(a[0],a[1],a[2],a[3],b[0],b[1],b[2],b[3]);
}
static __device__ __forceinline__ bf16x8 mk8r(f32x4 a, f32x4 b){ // relu + pack
  return mk8(fmaxf(a[0],0.f),fmaxf(a[1],0.f),fmaxf(a[2],0.f),fmaxf(a[3],0.f),
             fmaxf(b[0],0.f),fmaxf(b[1],0.f),fmaxf(b[2],0.f),fmaxf(b[3],0.f));
}
static __device__ __forceinline__ bf16x8 zero8(){
  bf16x8 v;
  #pragma unroll
  for(int i=0;i<8;++i) v[i]=0;
  return v;
}
static __device__ __forceinline__ bf16x8 one8(){   // [1.0, 0, ..., 0] in bf16
  bf16x8 v = zero8();
  v[0] = (short)0x3F80;
  return v;
}
static __device__ __forceinline__ void keepa(bf16x8& v){ asm("" : "+a"(v)); }
static __device__ __forceinline__ void keepaf(f32x4& v){ asm("" : "+a"(v)); }
static __device__ __forceinline__ void keepv(bf16x8& v){ asm("" : "+v"(v)); }
static __device__ __forceinline__ void keepvf(f32x4& v){ asm("" : "+v"(v)); }

// Layout (verified C/D layout, learn_hip m89):
//   A-frag: row = lane&15, k = (lane>>4)*8 + j
//   B-frag: col = lane&15, k = (lane>>4)*8 + j
//   C/D   : col = lane&15, row = (lane>>4)*4 + reg
// Scramble sigma on z / hidden features as in prior rounds.
//
// R14 = R12 (bias-fold, VERIFIED) + R6 2-tile stream duplication (VERIFIED),
// nothing else. R13's probs-form-y shelved (blew up, bug not found; rigor
// rule: one verified delta at a time). No prefetch regs: the B-stream and the
// co-resident wave provide the latency cover instead.
__global__ __launch_bounds__(256, 2) void trm_mfma(
    const float* __restrict__ state, const int* __restrict__ pact,
    const float* __restrict__ z0,
    const float* __restrict__ Wt1, const float* __restrict__ bt1,
    const float* __restrict__ Wt2, const float* __restrict__ bt2,
    const float* __restrict__ Wh1, const float* __restrict__ bh1,
    const float* __restrict__ Wh2, const float* __restrict__ bh2,
    const float* __restrict__ emb, float* __restrict__ out,
    int niters, int wstride)
{
  __shared__ __align__(16) float ef[64];          // emb 4x16 staged once
  const int lane = threadIdx.x & 63;
  const int wid  = blockIdx.x * (blockDim.x >> 6) + (threadIdx.x >> 6);
  const int r16  = lane & 15;
  const int hi   = lane >> 4;
  const int he   = hi & 1;

  if (threadIdx.x < 64) ef[threadIdx.x] = emb[threadIdx.x];
  __syncthreads();

  // ---- bt2 folds (prologue only; verified R12) ----------------------------
  f32x4 b2[8];
  #pragma unroll
  for (int q=0;q<8;++q) b2[q] = ld4(bt2 + q*4);
  float bt1p[4];
  #pragma unroll
  for (int m=0;m<4;++m){
    const float* w = Wt1 + (m*16 + r16)*112;
    f32x4 s = b2[0]*ld4(w);
    #pragma unroll
    for (int q=1;q<8;++q) s += b2[q]*ld4(w + q*4);
    bt1p[m] = bt1[m*16 + r16] + s[0]+s[1]+s[2]+s[3];
  }
  float bh1p[2];
  #pragma unroll
  for (int m=0;m<2;++m){
    const float* w = Wh1 + (m*16 + r16)*48;
    f32x4 s = b2[0]*ld4(w);
    #pragma unroll
    for (int q=1;q<8;++q) s += b2[q]*ld4(w + q*4);
    bh1p[m] = bh1[m*16 + r16] + s[0]+s[1]+s[2]+s[3];
  }

  // ------------- weights: persistent, pinned into the AGPR file ------------
  bf16x8 wt1f[4][4];
  #pragma unroll
  for (int m=0;m<4;++m){
    const float* w = Wt1 + (m*16 + r16)*112;
    wt1f[m][0] = mk8v(ld4(w + hi*4),       ld4(w + 16 + hi*4));   // z (scrambled)
    wt1f[m][1] = mk8v(ld4(w + 32 + hi*8),  ld4(w + 36 + hi*8));   // x[0:32]
    wt1f[m][2] = mk8v(ld4(w + 64 + hi*8),  ld4(w + 68 + hi*8));   // x[32:64]
    bf16x8 yfrag;                                                 // y | bias | 0
    if (hi < 2)       yfrag = mk8v(ld4(w + 96 + hi*8), ld4(w + 100 + hi*8));
    else if (hi == 2) yfrag = mk8(bt1p[m],0.f,0.f,0.f,0.f,0.f,0.f,0.f);
    else              yfrag = zero8();
    wt1f[m][3] = yfrag;
    keepa(wt1f[m][0]); keepa(wt1f[m][1]); keepa(wt1f[m][2]); keepa(wt1f[m][3]);
  }
  bf16x8 wt2f[2][2];
  #pragma unroll
  for (int m=0;m<2;++m){
    const float* w = Wt2 + (m*16 + r16)*64;
    wt2f[m][0] = mk8v(ld4(w + hi*4),      ld4(w + 16 + hi*4));    // h-cols scrambled
    wt2f[m][1] = mk8v(ld4(w + 32 + hi*4), ld4(w + 48 + hi*4));
    keepa(wt2f[m][0]); keepa(wt2f[m][1]);
  }
  bf16x8 wh1f[2][2];
  #pragma unroll
  for (int m=0;m<2;++m){
    const float* w = Wh1 + (m*16 + r16)*48;
    wh1f[m][0] = mk8v(ld4(w + hi*4), ld4(w + 16 + hi*4));         // z (scrambled)
    bf16x8 yfrag;                                                 // y | bias | 0
    if (hi < 2)       yfrag = mk8v(ld4(w + 32 + hi*8), ld4(w + 36 + hi*8));
    else if (hi == 2) yfrag = mk8(bh1p[m],0.f,0.f,0.f,0.f,0.f,0.f,0.f);
    else              yfrag = zero8();
    wh1f[m][1] = yfrag;
    keepa(wh1f[m][0]); keepa(wh1f[m][1]);
  }
  bf16x8 wh2f;
  {
    const float* w = Wh2 + ((r16 < 4) ? r16 : 0)*32;
    bf16x8 t = mk8v(ld4(w + hi*4), ld4(w + 16 + hi*4));           // h-cols scrambled
    if (r16 >= 4) t = zero8();                                    // pad rows 4..15
    wh2f = t;
    keepa(wh2f);
  }
  f32x4 bh2r;                                   // head L2 bias (C-init), AGPR
  {
    f32x4 t = ld4(bh2);
    bh2r = t * ((hi == 0) ? 1.f : 0.f);
    keepaf(bh2r);
  }
  f32x4 zero4 = {0.f, 0.f, 0.f, 0.f};           // shared C-init
  keepvf(zero4);
  bf16x8 z0f;                                   // (z0 - bt2), scrambled
  {
    f32x4 za = ld4(z0 + hi*4)      - ld4(bt2 + hi*4);
    f32x4 zb = ld4(z0 + 16 + hi*4) - ld4(bt2 + 16 + hi*4);
    z0f = mk8v(za, zb);
    keepv(z0f);
  }

  // ---------------- batch loop: 2 tiles (32 cols) per iteration ------------
  #pragma unroll 1
  for (int it = wid; it < niters; it += wstride){
    const int colA = it*32 + r16, colB = colA + 16;
    const float* xa = state + (size_t)colA*64;
    const float* xb = state + (size_t)colB*64;
    f32x4 ra0 = ld4(xa + hi*8),      ra1 = ld4(xa + hi*8 + 4);
    f32x4 ra2 = ld4(xa + 32 + hi*8), ra3 = ld4(xa + 36 + hi*8);
    f32x4 rb0 = ld4(xb + hi*8),      rb1 = ld4(xb + hi*8 + 4);
    f32x4 rb2 = ld4(xb + 32 + hi*8), rb3 = ld4(xb + 36 + hi*8);
    const int aA = pact[colA], aB = pact[colB];

    bf16x8 xfA0 = mk8v(ra0, ra1), xfA1 = mk8v(ra2, ra3);
    bf16x8 xfB0 = mk8v(rb0, rb1), xfB1 = mk8v(rb2, rb3);
    bf16x8 yfA, yfB;
    {
      const float* er = ef + aA*16 + he*8;
      yfA = mk8v(ld4(er), ld4(er + 4));
      if (hi == 2) yfA = one8();                // k=16 -> 1.0 (bias slot)
      if (hi == 3) yfA = zero8();
    }
    {
      const float* er = ef + aB*16 + he*8;
      yfB = mk8v(ld4(er), ld4(er + 4));
      if (hi == 2) yfB = one8();
      if (hi == 3) yfB = zero8();
    }
    bf16x8 zfA = z0f, zfB = z0f;
    f32x4 lgvA, lgvB;

    #pragma unroll
    for (int s = 0; s < 2; ++s){
      #pragma unroll
      for (int itr = 0; itr < 2; ++itr){
        f32x4 cA0 = MFMA16(wt1f[0][0], zfA, zero4);
        f32x4 cB0 = MFMA16(wt1f[0][0], zfB, zero4);
        f32x4 cA1 = MFMA16(wt1f[1][0], zfA, zero4);
        f32x4 cB1 = MFMA16(wt1f[1][0], zfB, zero4);
        f32x4 cA2 = MFMA16(wt1f[2][0], zfA, zero4);
        f32x4 cB2 = MFMA16(wt1f[2][0], zfB, zero4);
        f32x4 cA3 = MFMA16(wt1f[3][0], zfA, zero4);
        f32x4 cB3 = MFMA16(wt1f[3][0], zfB, zero4);
        cA0=MFMA16(wt1f[0][1], xfA0, cA0); cB0=MFMA16(wt1f[0][1], xfB0, cB0);
        cA1=MFMA16(wt1f[1][1], xfA0, cA1); cB1=MFMA16(wt1f[1][1], xfB0, cB1);
        cA2=MFMA16(wt1f[2][1], xfA0, cA2); cB2=MFMA16(wt1f[2][1], xfB0, cB2);
        cA3=MFMA16(wt1f[3][1], xfA0, cA3); cB3=MFMA16(wt1f[3][1], xfB0, cB3);
        cA0=MFMA16(wt1f[0][2], xfA1, cA0); cB0=MFMA16(wt1f[0][2], xfB1, cB0);
        cA1=MFMA16(wt1f[1][2], xfA1, cA1); cB1=MFMA16(wt1f[1][2], xfB1, cB1);
        cA2=MFMA16(wt1f[2][2], xfA1, cA2); cB2=MFMA16(wt1f[2][2], xfB1, cB2);
        cA3=MFMA16(wt1f[3][2], xfA1, cA3); cB3=MFMA16(wt1f[3][2], xfB1, cB3);
        cA0=MFMA16(wt1f[0][3], yfA, cA0);  cB0=MFMA16(wt1f[0][3], yfB, cB0);
        cA1=MFMA16(wt1f[1][3], yfA, cA1);  cB1=MFMA16(wt1f[1][3], yfB, cB1);
        cA2=MFMA16(wt1f[2][3], yfA, cA2);  cB2=MFMA16(wt1f[2][3], yfB, cB2);
        cA3=MFMA16(wt1f[3][3], yfA, cA3);  cB3=MFMA16(wt1f[3][3], yfB, cB3);
        bf16x8 hA0 = mk8r(cA0, cA1), hA1 = mk8r(cA2, cA3);
        bf16x8 hB0 = mk8r(cB0, cB1), hB1 = mk8r(cB2, cB3);
        f32x4 dA0 = MFMA16(wt2f[0][0], hA0, zero4);
        f32x4 dB0 = MFMA16(wt2f[0][0], hB0, zero4);
        f32x4 dA1 = MFMA16(wt2f[1][0], hA0, zero4);
        f32x4 dB1 = MFMA16(wt2f[1][0], hB0, zero4);
        dA0=MFMA16(wt2f[0][1], hA1, dA0); dB0=MFMA16(wt2f[0][1], hB1, dB0);
        dA1=MFMA16(wt2f[1][1], hA1, dA1); dB1=MFMA16(wt2f[1][1], hB1, dB1);
        zfA = mk8v(dA0, dA1); zfB = mk8v(dB0, dB1);   // zhat, in-lane
      }
      f32x4 gA0 = MFMA16(wh1f[0][0], zfA, zero4);
      f32x4 gB0 = MFMA16(wh1f[0][0], zfB, zero4);
      f32x4 gA1 = MFMA16(wh1f[1][0], zfA, zero4);
      f32x4 gB1 = MFMA16(wh1f[1][0], zfB, zero4);
      gA0=MFMA16(wh1f[0][1], yfA, gA0); gB0=MFMA16(wh1f[0][1], yfB, gB0);
      gA1=MFMA16(wh1f[1][1], yfA, gA1); gB1=MFMA16(wh1f[1][1], yfB, gB1);
      bf16x8 hhA = mk8r(gA0, gA1), hhB = mk8r(gB0, gB1);
      f32x4 clA = MFMA16(wh2f, hhA, bh2r);
      f32x4 clB = MFMA16(wh2f, hhB, bh2r);
      lgvA = clA; lgvB = clB;
      if (s == 0){
        {
          float l0=__shfl(clA[0],r16), l1=__shfl(clA[1],r16);
          float l2=__shfl(clA[2],r16), l3=__shfl(clA[3],r16);
          float mx = fmaxf(fmaxf(l0,l1), fmaxf(l2,l3));
          float p0=__expf(l0-mx), p1=__expf(l1-mx);
          float p2=__expf(l2-mx), p3=__expf(l3-mx);
          float inv = 1.f/(p0+p1+p2+p3);
          p0*=inv; p1*=inv; p2*=inv; p3*=inv;
          const float* eb = ef + he*8;
          f32x4 ya = ld4(eb)*p0    + ld4(eb+16)*p1 +
                     ld4(eb+32)*p2 + ld4(eb+48)*p3;
          f32x4 yb = ld4(eb+4)*p0  + ld4(eb+20)*p1 +
                     ld4(eb+36)*p2 + ld4(eb+52)*p3;
          yfA = mk8v(ya, yb);
          if (hi == 2) yfA = one8();
          if (hi == 3) yfA = zero8();
        }
        {
          float l0=__shfl(clB[0],r16), l1=__shfl(clB[1],r16);
          float l2=__shfl(clB[2],r16), l3=__shfl(clB[3],r16);
          float mx = fmaxf(fmaxf(l0,l1), fmaxf(l2,l3));
          float p0=__expf(l0-mx), p1=__expf(l1-mx);
          float p2=__expf(l2-mx), p3=__expf(l3-mx);
          float inv = 1.f/(p0+p1+p2+p3);
          p0*=inv; p1*=inv; p2*=inv; p3*=inv;
          const float* eb = ef + he*8;
          f32x4 ya = ld4(eb)*p0    + ld4(eb+16)*p1 +
                     ld4(eb+32)*p2 + ld4(eb+48)*p3;
          f32x4 yb = ld4(eb+4)*p0  + ld4(eb+20)*p1 +
                     ld4(eb+36)*p2 + ld4(eb+52)*p3;
          yfB = mk8v(ya, yb);
          if (hi == 2) yfB = one8();
          if (hi == 3) yfB = zero8();
        }
      }
    }
    if (hi == 0){
      *(f32x4*)(out + (size_t)colA*4) = lgvA;
      *(f32x4*)(out + (size_t)colB*4) = lgvB;
    }
  }
}

extern "C" void kernel_launch(void* const* d_in, const int* in_sizes, int n_in,
                              void* d_out, int out_size, void* d_ws, size_t ws_size,
                              hipStream_t stream) {
  const float* state = (const float*)d_in[0];
  const int*   pact  = (const int*)  d_in[1];
  const float* z0    = (const float*)d_in[2];
  const float* Wt1   = (const float*)d_in[3];
  const float* bt1   = (const float*)d_in[4];
  const float* Wt2   = (const float*)d_in[5];
  const float* bt2   = (const float*)d_in[6];
  const float* Wh1   = (const float*)d_in[7];
  const float* bh1   = (const float*)d_in[8];
  const float* Wh2   = (const float*)d_in[9];
  const float* bh2   = (const float*)d_in[10];
  const float* emb   = (const float*)d_in[11];
  float* out = (float*)d_out;

  const int B = in_sizes[0] / 64;         // 524288
  const int niters = B / 32;              // 16384 (2 tiles of 16 per iter)
  const int blocks = 512;                 // 2 blocks/CU, 4 waves each
  const int wstride = blocks * 4;         // 2048 waves -> 8 iters/wave
  trm_mfma<<<blocks, 256, 0, stream>>>(state, pact, z0, Wt1, bt1, Wt2, bt2,
                                       Wh1, bh1, Wh2, bh2, emb, out,
                                       niters, wstride);
}